// Round 9
// baseline (62072.089 us; speedup 1.0000x reference)
//
#include <hip/hip_runtime.h>
#include <math.h>

#define BB 128
#define TT 256
#define HH 512
#define VV 32
#define MLEN 128
#define NB 2              // batch columns per block
#define NBLK 64           // grid: NBLK * NB == BB

typedef long long ll;

// ---- workspace layout (float offsets) ----
#define TP_OFF   ((ll)BB * TT * HH)                 // emb-projection T [3*HH][VV]
#define W0T_OFF  (TP_OFF + (ll)3 * HH * VV)         // enc L0: f4(er,ez,en,0)[d][j]
#define W1A_OFF  (W0T_OFF + (ll)HH * HH * 4)        // enc L1: f4(f1r,f1z,f1n,g1r)[d][j]
#define W1B_OFF  (W1A_OFF + (ll)HH * HH * 4)        // enc L1: f2(g1z,g1n)[d][j]
#define D0A_OFF  (W1B_OFF + (ll)HH * HH * 2)        // dec L0: f4(c0r,c0z,c0n,u0r)[d][j]
#define D0B_OFF  (D0A_OFF + (ll)HH * HH * 4)        // dec L0: f2(u0z,u0n)[d][j]
#define D1A_OFF  (D0B_OFF + (ll)HH * HH * 2)        // dec L1: f4(c1r,c1z,c1n,u1r)[d][j]
#define D1B_OFF  (D1A_OFF + (ll)HH * HH * 4)        // dec L1: f2(u1z,u1n)[d][j]
#define QTT_OFF  (D1B_OFF + (ll)HH * HH * 2)        // qW^T: f4(4 d's)[d4][j]
#define WS_NEED_BYTES ((QTT_OFF + (ll)HH * HH) * 4) // ~91.4 MB

struct P {
    const float *x, *emb;
    const float *eWih0, *eWhh0, *ebih0, *ebhh0;
    const float *eWih1, *eWhh1, *ebih1, *ebhh1;
    const float *dWih0, *dWhh0, *dbih0, *dbhh0;
    const float *dWih1, *dWhh1, *dbih1, *dbhh1;
    const float *qW, *qb, *outW, *outb;
    float *ws;
    float *vecO, *hidO, *attnO;
};

__device__ __forceinline__ float sigf(float v) { return 1.0f / (1.0f + __expf(-v)); }
__device__ __forceinline__ float dot4(float4 a, float4 b, float acc) {
    return fmaf(a.x, b.x, fmaf(a.y, b.y, fmaf(a.z, b.z, fmaf(a.w, b.w, acc))));
}

// ---- prep: gate-packed weight transposes + emb-projection table (run once,
// stream-ordered before kmain; writes each element exactly once) ----
__global__ void kprep(P p) {
    const ll nt = (ll)gridDim.x * blockDim.x;
    const ll id0 = (ll)blockIdx.x * blockDim.x + threadIdx.x;
    float* ws = p.ws;
    for (ll i = id0; i < (ll)HH * HH; i += nt) {
        int d = (int)(i >> 9), j = (int)(i & 511);
        ((float4*)(ws + W0T_OFF))[i] = make_float4(
            p.eWhh0[(ll)j * HH + d], p.eWhh0[(ll)(HH + j) * HH + d],
            p.eWhh0[(ll)(2 * HH + j) * HH + d], 0.0f);
        ((float4*)(ws + W1A_OFF))[i] = make_float4(
            p.eWih1[(ll)j * HH + d], p.eWih1[(ll)(HH + j) * HH + d],
            p.eWih1[(ll)(2 * HH + j) * HH + d], p.eWhh1[(ll)j * HH + d]);
        ((float2*)(ws + W1B_OFF))[i] = make_float2(
            p.eWhh1[(ll)(HH + j) * HH + d], p.eWhh1[(ll)(2 * HH + j) * HH + d]);
        ((float4*)(ws + D0A_OFF))[i] = make_float4(
            p.dWih0[(ll)j * 1024 + 512 + d], p.dWih0[(ll)(HH + j) * 1024 + 512 + d],
            p.dWih0[(ll)(2 * HH + j) * 1024 + 512 + d], p.dWhh0[(ll)j * HH + d]);
        ((float2*)(ws + D0B_OFF))[i] = make_float2(
            p.dWhh0[(ll)(HH + j) * HH + d], p.dWhh0[(ll)(2 * HH + j) * HH + d]);
        ((float4*)(ws + D1A_OFF))[i] = make_float4(
            p.dWih1[(ll)j * HH + d], p.dWih1[(ll)(HH + j) * HH + d],
            p.dWih1[(ll)(2 * HH + j) * HH + d], p.dWhh1[(ll)j * HH + d]);
        ((float2*)(ws + D1B_OFF))[i] = make_float2(
            p.dWhh1[(ll)(HH + j) * HH + d], p.dWhh1[(ll)(2 * HH + j) * HH + d]);
    }
    // qW^T packed along d: entry d4*HH + j = qW[j][4*d4 .. 4*d4+3]
    for (ll i = id0; i < (ll)(HH / 4) * HH; i += nt) {
        int d4 = (int)(i >> 9), j = (int)(i & 511);
        const float* qr = p.qW + (ll)j * HH + d4 * 4;
        ((float4*)(ws + QTT_OFF))[i] = make_float4(qr[0], qr[1], qr[2], qr[3]);
    }
    // T[(g*HH+j)][v] = dot(dWih0[g*HH+j][0:512], emb[v])
    for (ll u = id0; u < (ll)3 * HH * VV; u += nt) {
        int v = (int)(u & 31), gj = (int)(u >> 5);
        const float* wrow = p.dWih0 + (ll)gj * 1024;
        const float* erow = p.emb + (ll)v * HH;
        float acc = 0.0f;
#pragma unroll 8
        for (int d = 0; d < HH; ++d) acc = fmaf(wrow[d], erow[d], acc);
        (ws + TP_OFF)[u] = acc;
    }
}

// Batch-partitioned main kernel: block owns NB batch columns; all mutable state
// block-private (LDS) -> no grid sync, no atomics. PK=1: packed weight streams.
template<int PK>
__global__ __launch_bounds__(512, 1) void kmain(P p) {
    __shared__ float h0m[2][NB][HH];
    __shared__ float h1m[2][NB][HH];
    __shared__ float qv[NB][HH];
    __shared__ float cx[NB][HH];
    __shared__ float sc[NB][TT];
    __shared__ float xl[NB][TT][2];
    __shared__ float embL[VV][HH];       // used only in fallback (PK=0)
    __shared__ float red[NB][8][VV];
    __shared__ float lgs[NB][VV];
    __shared__ float mred[NB][8];
    __shared__ int tkn[NB];

    const int tid = threadIdx.x;
    const int blk = blockIdx.x;
    const int j = tid;
    const int bgl = blk * NB;
    float* ws = p.ws;
    float* encO = ws;                    // [128 b][256 t][512 j]
    float* Tp = ws + TP_OFF;

    // ================= INIT =================
    for (int i = tid; i < NB * TT * 2; i += 512) {
        int b = i >> 9, r = i & 511, t = r >> 1, c = r & 1;
        xl[b][t][c] = p.x[((ll)(bgl + b) * TT + t) * 2 + c];
    }
    h0m[0][0][j] = 0.0f; h0m[0][1][j] = 0.0f;
    h1m[0][0][j] = 0.0f; h1m[0][1][j] = 0.0f;
    if constexpr (!PK) {
        for (int i = tid; i < VV * HH; i += 512) embL[i >> 9][i & 511] = p.emb[i];
    }
    __syncthreads();
    if constexpr (!PK) {
        // per-block redundant T compute (identical values, benign)
        for (int g = 0; g < 3; ++g) {
            const float4* wrow = (const float4*)(p.dWih0 + (ll)(g * HH + j) * 1024);
            float acc[VV];
#pragma unroll
            for (int v = 0; v < VV; ++v) acc[v] = 0.0f;
            for (int d4 = 0; d4 < HH / 4; ++d4) {
                float4 w = wrow[d4];
#pragma unroll
                for (int v = 0; v < VV; ++v)
                    acc[v] = dot4(w, ((const float4*)embL[v])[d4], acc[v]);
            }
            for (int v = 0; v < VV; ++v) Tp[(ll)(g * HH + j) * VV + v] = acc[v];
        }
    }

    int cur = 0;

    // fallback weight row pointers (unused/DCE'd when PK=1)
    const float4* er = (const float4*)(p.eWhh0 + (ll)j * HH);
    const float4* ez = (const float4*)(p.eWhh0 + (ll)(HH + j) * HH);
    const float4* en = (const float4*)(p.eWhh0 + (ll)(2 * HH + j) * HH);
    const float4* f1r = (const float4*)(p.eWih1 + (ll)j * HH);
    const float4* f1z = (const float4*)(p.eWih1 + (ll)(HH + j) * HH);
    const float4* f1n = (const float4*)(p.eWih1 + (ll)(2 * HH + j) * HH);
    const float4* g1r = (const float4*)(p.eWhh1 + (ll)j * HH);
    const float4* g1z = (const float4*)(p.eWhh1 + (ll)(HH + j) * HH);
    const float4* g1n = (const float4*)(p.eWhh1 + (ll)(2 * HH + j) * HH);

    const float wxr0 = p.eWih0[j * 2],            wxr1 = p.eWih0[j * 2 + 1];
    const float wxz0 = p.eWih0[(HH + j) * 2],     wxz1 = p.eWih0[(HH + j) * 2 + 1];
    const float wxn0 = p.eWih0[(2 * HH + j) * 2], wxn1 = p.eWih0[(2 * HH + j) * 2 + 1];
    const float bir = p.ebih0[j], biz = p.ebih0[HH + j], bin_ = p.ebih0[2 * HH + j];
    const float bhr = p.ebhh0[j], bhz = p.ebhh0[HH + j], bhn = p.ebhh0[2 * HH + j];
    const float cir = p.ebih1[j] + p.ebhh1[j];
    const float ciz = p.ebih1[HH + j] + p.ebhh1[HH + j];
    const float cin = p.ebih1[2 * HH + j];
    const float chn = p.ebhh1[2 * HH + j];

    // ================= ENCODER =================
    for (int t = 0; t < TT; ++t) {
        const int nxt = cur ^ 1;
        // layer 0
        {
            float ar0 = 0, az0 = 0, an0 = 0, ar1 = 0, az1 = 0, an1 = 0;
            const float4* ha = (const float4*)h0m[cur][0];
            const float4* hb = (const float4*)h0m[cur][1];
            if constexpr (PK) {
                const float4* w0 = (const float4*)(ws + W0T_OFF);
                for (int d4 = 0; d4 < HH / 4; ++d4) {
                    float4 a4 = ha[d4], b4 = hb[d4];
                    float aa[4] = {a4.x, a4.y, a4.z, a4.w};
                    float bb[4] = {b4.x, b4.y, b4.z, b4.w};
#pragma unroll
                    for (int u = 0; u < 4; ++u) {
                        float4 w = w0[(d4 * 4 + u) * HH + j];
                        ar0 = fmaf(w.x, aa[u], ar0); az0 = fmaf(w.y, aa[u], az0); an0 = fmaf(w.z, aa[u], an0);
                        ar1 = fmaf(w.x, bb[u], ar1); az1 = fmaf(w.y, bb[u], az1); an1 = fmaf(w.z, bb[u], an1);
                    }
                }
            } else {
#pragma unroll 4
                for (int d4 = 0; d4 < HH / 4; ++d4) {
                    float4 wr = er[d4], wz = ez[d4], wn = en[d4];
                    float4 a = ha[d4], b = hb[d4];
                    ar0 = dot4(wr, a, ar0); ar1 = dot4(wr, b, ar1);
                    az0 = dot4(wz, a, az0); az1 = dot4(wz, b, az1);
                    an0 = dot4(wn, a, an0); an1 = dot4(wn, b, an1);
                }
            }
            float x00 = xl[0][t][0], x01 = xl[0][t][1];
            float x10 = xl[1][t][0], x11 = xl[1][t][1];
            float r0 = sigf(fmaf(wxr0, x00, fmaf(wxr1, x01, bir)) + ar0 + bhr);
            float z0 = sigf(fmaf(wxz0, x00, fmaf(wxz1, x01, biz)) + az0 + bhz);
            float n0 = tanhf(fmaf(wxn0, x00, fmaf(wxn1, x01, bin_)) + r0 * (an0 + bhn));
            h0m[nxt][0][j] = (1.0f - z0) * n0 + z0 * h0m[cur][0][j];
            float r1 = sigf(fmaf(wxr0, x10, fmaf(wxr1, x11, bir)) + ar1 + bhr);
            float z1 = sigf(fmaf(wxz0, x10, fmaf(wxz1, x11, biz)) + az1 + bhz);
            float n1 = tanhf(fmaf(wxn0, x10, fmaf(wxn1, x11, bin_)) + r1 * (an1 + bhn));
            h0m[nxt][1][j] = (1.0f - z1) * n1 + z1 * h0m[cur][1][j];
        }
        __syncthreads();
        // layer 1 (input = new h0)
        {
            float pr0 = 0, pz0 = 0, pn0 = 0, pr1 = 0, pz1 = 0, pn1 = 0;
            float hr0 = 0, hz0 = 0, hn0 = 0, hr1 = 0, hz1 = 0, hn1 = 0;
            const float4* ya = (const float4*)h0m[nxt][0];
            const float4* yb = (const float4*)h0m[nxt][1];
            const float4* ha = (const float4*)h1m[cur][0];
            const float4* hb = (const float4*)h1m[cur][1];
            if constexpr (PK) {
                const float4* wA = (const float4*)(ws + W1A_OFF);
                const float2* wB = (const float2*)(ws + W1B_OFF);
                for (int d4 = 0; d4 < HH / 4; ++d4) {
                    float4 a4 = ya[d4], b4 = yb[d4], c4 = ha[d4], e4 = hb[d4];
                    float aa[4] = {a4.x, a4.y, a4.z, a4.w};
                    float bb[4] = {b4.x, b4.y, b4.z, b4.w};
                    float cc[4] = {c4.x, c4.y, c4.z, c4.w};
                    float ee[4] = {e4.x, e4.y, e4.z, e4.w};
#pragma unroll
                    for (int u = 0; u < 4; ++u) {
                        float4 wa = wA[(d4 * 4 + u) * HH + j];
                        float2 wb = wB[(d4 * 4 + u) * HH + j];
                        pr0 = fmaf(wa.x, aa[u], pr0); pz0 = fmaf(wa.y, aa[u], pz0); pn0 = fmaf(wa.z, aa[u], pn0);
                        hr0 = fmaf(wa.w, cc[u], hr0); hz0 = fmaf(wb.x, cc[u], hz0); hn0 = fmaf(wb.y, cc[u], hn0);
                        pr1 = fmaf(wa.x, bb[u], pr1); pz1 = fmaf(wa.y, bb[u], pz1); pn1 = fmaf(wa.z, bb[u], pn1);
                        hr1 = fmaf(wa.w, ee[u], hr1); hz1 = fmaf(wb.x, ee[u], hz1); hn1 = fmaf(wb.y, ee[u], hn1);
                    }
                }
            } else {
#pragma unroll 2
                for (int d4 = 0; d4 < HH / 4; ++d4) {
                    float4 a = ya[d4], b = yb[d4], c = ha[d4], d = hb[d4];
                    float4 w;
                    w = f1r[d4]; pr0 = dot4(w, a, pr0); pr1 = dot4(w, b, pr1);
                    w = f1z[d4]; pz0 = dot4(w, a, pz0); pz1 = dot4(w, b, pz1);
                    w = f1n[d4]; pn0 = dot4(w, a, pn0); pn1 = dot4(w, b, pn1);
                    w = g1r[d4]; hr0 = dot4(w, c, hr0); hr1 = dot4(w, d, hr1);
                    w = g1z[d4]; hz0 = dot4(w, c, hz0); hz1 = dot4(w, d, hz1);
                    w = g1n[d4]; hn0 = dot4(w, c, hn0); hn1 = dot4(w, d, hn1);
                }
            }
            float r0 = sigf(pr0 + hr0 + cir);
            float z0 = sigf(pz0 + hz0 + ciz);
            float n0 = tanhf(pn0 + cin + r0 * (hn0 + chn));
            float hv0 = (1.0f - z0) * n0 + z0 * h1m[cur][0][j];
            h1m[nxt][0][j] = hv0;
            encO[((ll)(bgl + 0) * TT + t) * HH + j] = hv0;
            float r1 = sigf(pr1 + hr1 + cir);
            float z1 = sigf(pz1 + hz1 + ciz);
            float n1 = tanhf(pn1 + cin + r1 * (hn1 + chn));
            float hv1 = (1.0f - z1) * n1 + z1 * h1m[cur][1][j];
            h1m[nxt][1][j] = hv1;
            encO[((ll)(bgl + 1) * TT + t) * HH + j] = hv1;
        }
        __syncthreads();
        cur ^= 1;
    }

    // ================= DEC-INIT =================
    const float qbj = p.qb[j];
    const float4* qw4 = (const float4*)(p.qW + (ll)j * HH);
    const float4* qt4 = (const float4*)(ws + QTT_OFF);
    {
        const float4* ha = (const float4*)h1m[cur][0];
        const float4* hb = (const float4*)h1m[cur][1];
        float a0 = 0, a1 = 0;
#pragma unroll 4
        for (int d4 = 0; d4 < HH / 4; ++d4) {
            float4 w = PK ? qt4[d4 * HH + j] : qw4[d4];
            a0 = dot4(w, ha[d4], a0); a1 = dot4(w, hb[d4], a1);
        }
        qv[0][j] = a0 + qbj; qv[1][j] = a1 + qbj;
    }
    if (tid < NB) tkn[tid] = 0;
    __syncthreads();

    // fallback decoder row pointers
    const float4* c0r = (const float4*)(p.dWih0 + (ll)j * 1024 + 512);
    const float4* c0z = (const float4*)(p.dWih0 + (ll)(HH + j) * 1024 + 512);
    const float4* c0n = (const float4*)(p.dWih0 + (ll)(2 * HH + j) * 1024 + 512);
    const float4* u0r = (const float4*)(p.dWhh0 + (ll)j * HH);
    const float4* u0z = (const float4*)(p.dWhh0 + (ll)(HH + j) * HH);
    const float4* u0n = (const float4*)(p.dWhh0 + (ll)(2 * HH + j) * HH);
    const float4* c1r = (const float4*)(p.dWih1 + (ll)j * HH);
    const float4* c1z = (const float4*)(p.dWih1 + (ll)(HH + j) * HH);
    const float4* c1n = (const float4*)(p.dWih1 + (ll)(2 * HH + j) * HH);
    const float4* u1r = (const float4*)(p.dWhh1 + (ll)j * HH);
    const float4* u1z = (const float4*)(p.dWhh1 + (ll)(HH + j) * HH);
    const float4* u1n = (const float4*)(p.dWhh1 + (ll)(2 * HH + j) * HH);
    const float* Trj = Tp + (ll)j * VV;
    const float* Tzj = Tp + (ll)(HH + j) * VV;
    const float* Tnj = Tp + (ll)(2 * HH + j) * VV;
    const float d0r = p.dbih0[j] + p.dbhh0[j];
    const float d0z = p.dbih0[HH + j] + p.dbhh0[HH + j];
    const float d0in = p.dbih0[2 * HH + j];
    const float d0hn = p.dbhh0[2 * HH + j];
    const float d1r = p.dbih1[j] + p.dbhh1[j];
    const float d1z = p.dbih1[HH + j] + p.dbhh1[HH + j];
    const float d1in = p.dbih1[2 * HH + j];
    const float d1hn = p.dbhh1[2 * HH + j];

    // ================= DECODER =================
    for (int s = 0; s < MLEN; ++s) {
        const int nxt = cur ^ 1;
        // scores
        {
            int b = tid >> 8, t = tid & 255;
            const float4* eRow = (const float4*)(encO + ((ll)(bgl + b) * TT + t) * HH);
            const float4* q4 = (const float4*)qv[b];
            float a = 0;
#pragma unroll 4
            for (int d4 = 0; d4 < HH / 4; ++d4) a = dot4(q4[d4], eRow[d4], a);
            sc[b][t] = a;
        }
        __syncthreads();
        if (tid < 128) {
            int b = tid >> 6, i = tid & 63;
            float m = fmaxf(fmaxf(sc[b][i], sc[b][i + 64]),
                            fmaxf(sc[b][i + 128], sc[b][i + 192]));
            for (int o = 32; o > 0; o >>= 1) m = fmaxf(m, __shfl_down(m, o));
            if (i == 0) mred[b][0] = m;
        }
        __syncthreads();
        {
            int b = tid >> 8, t = tid & 255;
            float e = __expf(sc[b][t] - mred[b][0]);
            sc[b][t] = e;
            float ssum = e;
            for (int o = 32; o > 0; o >>= 1) ssum += __shfl_down(ssum, o);
            if ((tid & 63) == 0) mred[b][1 + ((tid >> 6) & 3)] = ssum;
        }
        __syncthreads();
        {
            int b = tid >> 8, t = tid & 255;
            float l = mred[b][1] + mred[b][2] + mred[b][3] + mred[b][4];
            float w = sc[b][t] / l;
            sc[b][t] = w;
            p.attnO[((ll)(bgl + b) * MLEN + s) * TT + t] = w;
        }
        __syncthreads();
        // context
        {
            float c0 = 0, c1 = 0;
            const float* e0 = encO + (ll)(bgl + 0) * TT * HH + j;
            const float* e1 = encO + (ll)(bgl + 1) * TT * HH + j;
#pragma unroll 4
            for (int t2 = 0; t2 < TT; ++t2) {
                c0 = fmaf(sc[0][t2], e0[(ll)t2 * HH], c0);
                c1 = fmaf(sc[1][t2], e1[(ll)t2 * HH], c1);
            }
            cx[0][j] = c0; cx[1][j] = c1;
        }
        __syncthreads();
        // G0
        {
            const int tk0 = tkn[0], tk1 = tkn[1];
            float pr0 = 0, pz0 = 0, pn0 = 0, pr1 = 0, pz1 = 0, pn1 = 0;
            float hr0 = 0, hz0 = 0, hn0 = 0, hr1 = 0, hz1 = 0, hn1 = 0;
            const float4* xa = (const float4*)cx[0];
            const float4* xb = (const float4*)cx[1];
            const float4* ha = (const float4*)h0m[cur][0];
            const float4* hb = (const float4*)h0m[cur][1];
            if constexpr (PK) {
                const float4* wA = (const float4*)(ws + D0A_OFF);
                const float2* wB = (const float2*)(ws + D0B_OFF);
                for (int d4 = 0; d4 < HH / 4; ++d4) {
                    float4 a4 = xa[d4], b4 = xb[d4], c4 = ha[d4], e4 = hb[d4];
                    float aa[4] = {a4.x, a4.y, a4.z, a4.w};
                    float bb[4] = {b4.x, b4.y, b4.z, b4.w};
                    float cc[4] = {c4.x, c4.y, c4.z, c4.w};
                    float ee[4] = {e4.x, e4.y, e4.z, e4.w};
#pragma unroll
                    for (int u = 0; u < 4; ++u) {
                        float4 wa = wA[(d4 * 4 + u) * HH + j];
                        float2 wb = wB[(d4 * 4 + u) * HH + j];
                        pr0 = fmaf(wa.x, aa[u], pr0); pz0 = fmaf(wa.y, aa[u], pz0); pn0 = fmaf(wa.z, aa[u], pn0);
                        hr0 = fmaf(wa.w, cc[u], hr0); hz0 = fmaf(wb.x, cc[u], hz0); hn0 = fmaf(wb.y, cc[u], hn0);
                        pr1 = fmaf(wa.x, bb[u], pr1); pz1 = fmaf(wa.y, bb[u], pz1); pn1 = fmaf(wa.z, bb[u], pn1);
                        hr1 = fmaf(wa.w, ee[u], hr1); hz1 = fmaf(wb.x, ee[u], hz1); hn1 = fmaf(wb.y, ee[u], hn1);
                    }
                }
            } else {
#pragma unroll 2
                for (int d4 = 0; d4 < HH / 4; ++d4) {
                    float4 a = xa[d4], b = xb[d4], c = ha[d4], d = hb[d4];
                    float4 w;
                    w = c0r[d4]; pr0 = dot4(w, a, pr0); pr1 = dot4(w, b, pr1);
                    w = c0z[d4]; pz0 = dot4(w, a, pz0); pz1 = dot4(w, b, pz1);
                    w = c0n[d4]; pn0 = dot4(w, a, pn0); pn1 = dot4(w, b, pn1);
                    w = u0r[d4]; hr0 = dot4(w, c, hr0); hr1 = dot4(w, d, hr1);
                    w = u0z[d4]; hz0 = dot4(w, c, hz0); hz1 = dot4(w, d, hz1);
                    w = u0n[d4]; hn0 = dot4(w, c, hn0); hn1 = dot4(w, d, hn1);
                }
            }
            float r0 = sigf(Trj[tk0] + pr0 + hr0 + d0r);
            float z0 = sigf(Tzj[tk0] + pz0 + hz0 + d0z);
            float n0 = tanhf(Tnj[tk0] + pn0 + d0in + r0 * (hn0 + d0hn));
            h0m[nxt][0][j] = (1.0f - z0) * n0 + z0 * h0m[cur][0][j];
            float r1 = sigf(Trj[tk1] + pr1 + hr1 + d0r);
            float z1 = sigf(Tzj[tk1] + pz1 + hz1 + d0z);
            float n1 = tanhf(Tnj[tk1] + pn1 + d0in + r1 * (hn1 + d0hn));
            h0m[nxt][1][j] = (1.0f - z1) * n1 + z1 * h0m[cur][1][j];
        }
        __syncthreads();
        // G1
        {
            float pr0 = 0, pz0 = 0, pn0 = 0, pr1 = 0, pz1 = 0, pn1 = 0;
            float hr0 = 0, hz0 = 0, hn0 = 0, hr1 = 0, hz1 = 0, hn1 = 0;
            const float4* ya = (const float4*)h0m[nxt][0];
            const float4* yb = (const float4*)h0m[nxt][1];
            const float4* ha = (const float4*)h1m[cur][0];
            const float4* hb = (const float4*)h1m[cur][1];
            if constexpr (PK) {
                const float4* wA = (const float4*)(ws + D1A_OFF);
                const float2* wB = (const float2*)(ws + D1B_OFF);
                for (int d4 = 0; d4 < HH / 4; ++d4) {
                    float4 a4 = ya[d4], b4 = yb[d4], c4 = ha[d4], e4 = hb[d4];
                    float aa[4] = {a4.x, a4.y, a4.z, a4.w};
                    float bb[4] = {b4.x, b4.y, b4.z, b4.w};
                    float cc[4] = {c4.x, c4.y, c4.z, c4.w};
                    float ee[4] = {e4.x, e4.y, e4.z, e4.w};
#pragma unroll
                    for (int u = 0; u < 4; ++u) {
                        float4 wa = wA[(d4 * 4 + u) * HH + j];
                        float2 wb = wB[(d4 * 4 + u) * HH + j];
                        pr0 = fmaf(wa.x, aa[u], pr0); pz0 = fmaf(wa.y, aa[u], pz0); pn0 = fmaf(wa.z, aa[u], pn0);
                        hr0 = fmaf(wa.w, cc[u], hr0); hz0 = fmaf(wb.x, cc[u], hz0); hn0 = fmaf(wb.y, cc[u], hn0);
                        pr1 = fmaf(wa.x, bb[u], pr1); pz1 = fmaf(wa.y, bb[u], pz1); pn1 = fmaf(wa.z, bb[u], pn1);
                        hr1 = fmaf(wa.w, ee[u], hr1); hz1 = fmaf(wb.x, ee[u], hz1); hn1 = fmaf(wb.y, ee[u], hn1);
                    }
                }
            } else {
#pragma unroll 2
                for (int d4 = 0; d4 < HH / 4; ++d4) {
                    float4 a = ya[d4], b = yb[d4], c = ha[d4], d = hb[d4];
                    float4 w;
                    w = c1r[d4]; pr0 = dot4(w, a, pr0); pr1 = dot4(w, b, pr1);
                    w = c1z[d4]; pz0 = dot4(w, a, pz0); pz1 = dot4(w, b, pz1);
                    w = c1n[d4]; pn0 = dot4(w, a, pn0); pn1 = dot4(w, b, pn1);
                    w = u1r[d4]; hr0 = dot4(w, c, hr0); hr1 = dot4(w, d, hr1);
                    w = u1z[d4]; hz0 = dot4(w, c, hz0); hz1 = dot4(w, d, hz1);
                    w = u1n[d4]; hn0 = dot4(w, c, hn0); hn1 = dot4(w, d, hn1);
                }
            }
            float r0 = sigf(pr0 + hr0 + d1r);
            float z0 = sigf(pz0 + hz0 + d1z);
            float n0 = tanhf(pn0 + d1in + r0 * (hn0 + d1hn));
            h1m[nxt][0][j] = (1.0f - z0) * n0 + z0 * h1m[cur][0][j];
            float r1 = sigf(pr1 + hr1 + d1r);
            float z1 = sigf(pz1 + hz1 + d1z);
            float n1 = tanhf(pn1 + d1in + r1 * (hn1 + d1hn));
            h1m[nxt][1][j] = (1.0f - z1) * n1 + z1 * h1m[cur][1][j];
        }
        __syncthreads();
        // next-step query
        {
            const float4* ha = (const float4*)h1m[nxt][0];
            const float4* hb = (const float4*)h1m[nxt][1];
            float a0 = 0, a1 = 0;
#pragma unroll 4
            for (int d4 = 0; d4 < HH / 4; ++d4) {
                float4 w = PK ? qt4[d4 * HH + j] : qw4[d4];
                a0 = dot4(w, ha[d4], a0); a1 = dot4(w, hb[d4], a1);
            }
            qv[0][j] = a0 + qbj; qv[1][j] = a1 + qbj;
        }
        // logits
        {
            int v = tid & 31, ch = (tid >> 5) & 7, b = tid >> 8;
            const float4* wrow = (const float4*)(p.outW + (ll)v * HH + ch * 64);
            const float4* hrow = (const float4*)(&h1m[nxt][b][ch * 64]);
            float a = 0;
#pragma unroll
            for (int d4 = 0; d4 < 16; ++d4) a = dot4(wrow[d4], hrow[d4], a);
            red[b][ch][v] = a;
        }
        __syncthreads();
        if (tid < 64) {
            int b = tid >> 5, v = tid & 31;
            float a = red[b][0][v] + red[b][1][v] + red[b][2][v] + red[b][3][v] +
                      red[b][4][v] + red[b][5][v] + red[b][6][v] + red[b][7][v] +
                      p.outb[v];
            lgs[b][v] = a;
            p.vecO[((ll)(bgl + b) * MLEN + s) * VV + v] = a;
        }
        __syncthreads();
        if (tid < NB) {
            float best = lgs[tid][0];
            int bi = 0;
#pragma unroll
            for (int v = 1; v < VV; ++v) {
                float val = lgs[tid][v];
                if (val > best) { best = val; bi = v; }
            }
            tkn[tid] = bi;
        }
        cur ^= 1;
        __syncthreads();
    }

    // ================= final hidden [2][128][512] =================
    p.hidO[(ll)(bgl + 0) * HH + j] = h0m[cur][0][j];
    p.hidO[(ll)(bgl + 1) * HH + j] = h0m[cur][1][j];
    p.hidO[(ll)BB * HH + (ll)(bgl + 0) * HH + j] = h1m[cur][0][j];
    p.hidO[(ll)BB * HH + (ll)(bgl + 1) * HH + j] = h1m[cur][1][j];
}

extern "C" void kernel_launch(void* const* d_in, const int* in_sizes, int n_in,
                              void* d_out, int out_size, void* d_ws, size_t ws_size,
                              hipStream_t stream) {
    (void)in_sizes; (void)n_in; (void)out_size;
    P prm;
    prm.x     = (const float*)d_in[0];
    prm.emb   = (const float*)d_in[1];
    prm.eWih0 = (const float*)d_in[2];
    prm.eWhh0 = (const float*)d_in[3];
    prm.ebih0 = (const float*)d_in[4];
    prm.ebhh0 = (const float*)d_in[5];
    prm.eWih1 = (const float*)d_in[6];
    prm.eWhh1 = (const float*)d_in[7];
    prm.ebih1 = (const float*)d_in[8];
    prm.ebhh1 = (const float*)d_in[9];
    prm.dWih0 = (const float*)d_in[10];
    prm.dWhh0 = (const float*)d_in[11];
    prm.dbih0 = (const float*)d_in[12];
    prm.dbhh0 = (const float*)d_in[13];
    prm.dWih1 = (const float*)d_in[14];
    prm.dWhh1 = (const float*)d_in[15];
    prm.dbih1 = (const float*)d_in[16];
    prm.dbhh1 = (const float*)d_in[17];
    prm.qW    = (const float*)d_in[18];
    prm.qb    = (const float*)d_in[19];
    prm.outW  = (const float*)d_in[20];
    prm.outb  = (const float*)d_in[21];
    prm.ws    = (float*)d_ws;
    prm.vecO  = (float*)d_out;
    prm.hidO  = prm.vecO + (ll)BB * MLEN * VV;
    prm.attnO = prm.hidO + (ll)2 * BB * HH;

    if (ws_size >= (size_t)WS_NEED_BYTES) {
        hipLaunchKernelGGL(kprep, dim3(256), dim3(512), 0, stream, prm);
        hipLaunchKernelGGL(HIP_KERNEL_NAME(kmain<1>), dim3(NBLK), dim3(512), 0, stream, prm);
    } else {
        hipLaunchKernelGGL(HIP_KERNEL_NAME(kmain<0>), dim3(NBLK), dim3(512), 0, stream, prm);
    }
}

// Round 10
// 45822.946 us; speedup vs baseline: 1.3546x; 1.3546x over previous
//
#include <hip/hip_runtime.h>
#include <math.h>

#define BB 128
#define TT 256
#define HH 512
#define VV 32
#define MLEN 128
#define NBLK 128          // one batch column per block

typedef long long ll;

// ---- workspace layout (float offsets) ----
#define TP_OFF   ((ll)BB * TT * HH)                 // emb-projection T [3*HH][VV]
#define W0T_OFF  (TP_OFF + (ll)3 * HH * VV)         // enc L0: f4(er,ez,en,0)[d][j]
#define W1A_OFF  (W0T_OFF + (ll)HH * HH * 4)        // enc L1: f4(f1r,f1z,f1n,g1r)[d][j]
#define W1B_OFF  (W1A_OFF + (ll)HH * HH * 4)        // enc L1: f2(g1z,g1n)[d][j]
#define D0A_OFF  (W1B_OFF + (ll)HH * HH * 2)        // dec L0: f4(c0r,c0z,c0n,u0r)[d][j]
#define D0B_OFF  (D0A_OFF + (ll)HH * HH * 4)        // dec L0: f2(u0z,u0n)[d][j]
#define D1A_OFF  (D0B_OFF + (ll)HH * HH * 2)        // dec L1: f4(c1r,c1z,c1n,u1r)[d][j]
#define D1B_OFF  (D1A_OFF + (ll)HH * HH * 4)        // dec L1: f2(u1z,u1n)[d][j]
#define QTT_OFF  (D1B_OFF + (ll)HH * HH * 2)        // qW^T: f4(4 d's)[d4][j]
#define WS_NEED_BYTES ((QTT_OFF + (ll)HH * HH) * 4) // ~91.4 MB

struct P {
    const float *x, *emb;
    const float *eWih0, *eWhh0, *ebih0, *ebhh0;
    const float *eWih1, *eWhh1, *ebih1, *ebhh1;
    const float *dWih0, *dWhh0, *dbih0, *dbhh0;
    const float *dWih1, *dWhh1, *dbih1, *dbhh1;
    const float *qW, *qb, *outW, *outb;
    float *ws;
    float *vecO, *hidO, *attnO;
};

__device__ __forceinline__ float sigf(float v) { return 1.0f / (1.0f + __expf(-v)); }
__device__ __forceinline__ float dot4(float4 a, float4 b, float acc) {
    return fmaf(a.x, b.x, fmaf(a.y, b.y, fmaf(a.z, b.z, fmaf(a.w, b.w, acc))));
}

#define G6(WA, WB, iv, hv)                                                     \
    do {                                                                       \
        pr = fmaf((WA).x, (iv), pr); pz = fmaf((WA).y, (iv), pz);              \
        pn = fmaf((WA).z, (iv), pn); hr = fmaf((WA).w, (hv), hr);              \
        hz = fmaf((WB).x, (hv), hz); hn = fmaf((WB).y, (hv), hn);              \
    } while (0)

// 6-gate packed GEMV slice for output j: 2-chunk-deep register prefetch.
__device__ __forceinline__ void gemv6_pk(const float4* wA, const float2* wB,
                                         const float4* iv, const float4* hv, int j,
                                         float& pr_, float& pz_, float& pn_,
                                         float& hr_, float& hz_, float& hn_) {
    float pr = 0, pz = 0, pn = 0, hr = 0, hz = 0, hn = 0;
    float4 A0 = wA[0 * HH + j], A1 = wA[1 * HH + j], A2 = wA[2 * HH + j], A3 = wA[3 * HH + j];
    float2 b0 = wB[0 * HH + j], b1 = wB[1 * HH + j], b2 = wB[2 * HH + j], b3 = wB[3 * HH + j];
    for (int d4 = 0; d4 < HH / 4; d4 += 2) {
        float4 C0 = wA[((d4 + 1) * 4 + 0) * HH + j];
        float4 C1 = wA[((d4 + 1) * 4 + 1) * HH + j];
        float4 C2 = wA[((d4 + 1) * 4 + 2) * HH + j];
        float4 C3 = wA[((d4 + 1) * 4 + 3) * HH + j];
        float2 e0 = wB[((d4 + 1) * 4 + 0) * HH + j];
        float2 e1 = wB[((d4 + 1) * 4 + 1) * HH + j];
        float2 e2 = wB[((d4 + 1) * 4 + 2) * HH + j];
        float2 e3 = wB[((d4 + 1) * 4 + 3) * HH + j];
        float4 a4 = iv[d4], c4 = hv[d4];
        G6(A0, b0, a4.x, c4.x); G6(A1, b1, a4.y, c4.y);
        G6(A2, b2, a4.z, c4.z); G6(A3, b3, a4.w, c4.w);
        if (d4 + 2 < HH / 4) {
            A0 = wA[((d4 + 2) * 4 + 0) * HH + j];
            A1 = wA[((d4 + 2) * 4 + 1) * HH + j];
            A2 = wA[((d4 + 2) * 4 + 2) * HH + j];
            A3 = wA[((d4 + 2) * 4 + 3) * HH + j];
            b0 = wB[((d4 + 2) * 4 + 0) * HH + j];
            b1 = wB[((d4 + 2) * 4 + 1) * HH + j];
            b2 = wB[((d4 + 2) * 4 + 2) * HH + j];
            b3 = wB[((d4 + 2) * 4 + 3) * HH + j];
        }
        float4 a4b = iv[d4 + 1], c4b = hv[d4 + 1];
        G6(C0, e0, a4b.x, c4b.x); G6(C1, e1, a4b.y, c4b.y);
        G6(C2, e2, a4b.z, c4b.z); G6(C3, e3, a4b.w, c4b.w);
    }
    pr_ = pr; pz_ = pz; pn_ = pn; hr_ = hr; hz_ = hz; hn_ = hn;
}

// ---- prep: gate-packed weight transposes + emb-projection table ----
__global__ void kprep(P p) {
    const ll nt = (ll)gridDim.x * blockDim.x;
    const ll id0 = (ll)blockIdx.x * blockDim.x + threadIdx.x;
    float* ws = p.ws;
    for (ll i = id0; i < (ll)HH * HH; i += nt) {
        int d = (int)(i >> 9), j = (int)(i & 511);
        ((float4*)(ws + W0T_OFF))[i] = make_float4(
            p.eWhh0[(ll)j * HH + d], p.eWhh0[(ll)(HH + j) * HH + d],
            p.eWhh0[(ll)(2 * HH + j) * HH + d], 0.0f);
        ((float4*)(ws + W1A_OFF))[i] = make_float4(
            p.eWih1[(ll)j * HH + d], p.eWih1[(ll)(HH + j) * HH + d],
            p.eWih1[(ll)(2 * HH + j) * HH + d], p.eWhh1[(ll)j * HH + d]);
        ((float2*)(ws + W1B_OFF))[i] = make_float2(
            p.eWhh1[(ll)(HH + j) * HH + d], p.eWhh1[(ll)(2 * HH + j) * HH + d]);
        ((float4*)(ws + D0A_OFF))[i] = make_float4(
            p.dWih0[(ll)j * 1024 + 512 + d], p.dWih0[(ll)(HH + j) * 1024 + 512 + d],
            p.dWih0[(ll)(2 * HH + j) * 1024 + 512 + d], p.dWhh0[(ll)j * HH + d]);
        ((float2*)(ws + D0B_OFF))[i] = make_float2(
            p.dWhh0[(ll)(HH + j) * HH + d], p.dWhh0[(ll)(2 * HH + j) * HH + d]);
        ((float4*)(ws + D1A_OFF))[i] = make_float4(
            p.dWih1[(ll)j * HH + d], p.dWih1[(ll)(HH + j) * HH + d],
            p.dWih1[(ll)(2 * HH + j) * HH + d], p.dWhh1[(ll)j * HH + d]);
        ((float2*)(ws + D1B_OFF))[i] = make_float2(
            p.dWhh1[(ll)(HH + j) * HH + d], p.dWhh1[(ll)(2 * HH + j) * HH + d]);
    }
    for (ll i = id0; i < (ll)(HH / 4) * HH; i += nt) {
        int d4 = (int)(i >> 9), j = (int)(i & 511);
        const float* qr = p.qW + (ll)j * HH + d4 * 4;
        ((float4*)(ws + QTT_OFF))[i] = make_float4(qr[0], qr[1], qr[2], qr[3]);
    }
    for (ll u = id0; u < (ll)3 * HH * VV; u += nt) {
        int v = (int)(u & 31), gj = (int)(u >> 5);
        const float* wrow = p.dWih0 + (ll)gj * 1024;
        const float* erow = p.emb + (ll)v * HH;
        float acc = 0.0f;
#pragma unroll 8
        for (int d = 0; d < HH; ++d) acc = fmaf(wrow[d], erow[d], acc);
        (ws + TP_OFF)[u] = acc;
    }
}

template<int PK>
__global__ __launch_bounds__(512, 1) void kmain(P p) {
    __shared__ float h0m[2][HH];
    __shared__ float h1m[2][HH];
    __shared__ float qv[HH];
    __shared__ float cx[HH];
    __shared__ float sc[TT];
    __shared__ float xl[TT][2];
    __shared__ float embL[VV][HH];       // PK=0 only (DCE'd otherwise)
    __shared__ float red[16][VV];
    __shared__ float lgs[VV];
    __shared__ float mred[8];
    __shared__ int tkn;

    const int tid = threadIdx.x;
    const int blk = blockIdx.x;
    const int j = tid;
    float* ws = p.ws;
    float* encO = ws;                    // [128 b][256 t][512 j]
    float* Tp = ws + TP_OFF;

    // ================= INIT =================
    {
        int t = tid >> 1, c = tid & 1;
        xl[t][c] = p.x[((ll)blk * TT + t) * 2 + c];
    }
    h0m[0][j] = 0.0f;
    h1m[0][j] = 0.0f;
    if constexpr (!PK) {
        for (int i = tid; i < VV * HH; i += 512) embL[i >> 9][i & 511] = p.emb[i];
    }
    __syncthreads();
    if constexpr (!PK) {
        for (int g = 0; g < 3; ++g) {
            const float4* wrow = (const float4*)(p.dWih0 + (ll)(g * HH + j) * 1024);
            float acc[VV];
#pragma unroll
            for (int v = 0; v < VV; ++v) acc[v] = 0.0f;
            for (int d4 = 0; d4 < HH / 4; ++d4) {
                float4 w = wrow[d4];
#pragma unroll
                for (int v = 0; v < VV; ++v)
                    acc[v] = dot4(w, ((const float4*)embL[v])[d4], acc[v]);
            }
            for (int v = 0; v < VV; ++v) Tp[(ll)(g * HH + j) * VV + v] = acc[v];
        }
    }

    int cur = 0;

    const float wxr0 = p.eWih0[j * 2],            wxr1 = p.eWih0[j * 2 + 1];
    const float wxz0 = p.eWih0[(HH + j) * 2],     wxz1 = p.eWih0[(HH + j) * 2 + 1];
    const float wxn0 = p.eWih0[(2 * HH + j) * 2], wxn1 = p.eWih0[(2 * HH + j) * 2 + 1];
    const float bir = p.ebih0[j], biz = p.ebih0[HH + j], bin_ = p.ebih0[2 * HH + j];
    const float bhr = p.ebhh0[j], bhz = p.ebhh0[HH + j], bhn = p.ebhh0[2 * HH + j];
    const float cir = p.ebih1[j] + p.ebhh1[j];
    const float ciz = p.ebih1[HH + j] + p.ebhh1[HH + j];
    const float cin = p.ebih1[2 * HH + j];
    const float chn = p.ebhh1[2 * HH + j];

    // fallback row pointers (DCE'd when PK=1)
    const float4* er = (const float4*)(p.eWhh0 + (ll)j * HH);
    const float4* ez = (const float4*)(p.eWhh0 + (ll)(HH + j) * HH);
    const float4* en = (const float4*)(p.eWhh0 + (ll)(2 * HH + j) * HH);
    const float4* f1r = (const float4*)(p.eWih1 + (ll)j * HH);
    const float4* f1z = (const float4*)(p.eWih1 + (ll)(HH + j) * HH);
    const float4* f1n = (const float4*)(p.eWih1 + (ll)(2 * HH + j) * HH);
    const float4* g1r = (const float4*)(p.eWhh1 + (ll)j * HH);
    const float4* g1z = (const float4*)(p.eWhh1 + (ll)(HH + j) * HH);
    const float4* g1n = (const float4*)(p.eWhh1 + (ll)(2 * HH + j) * HH);

    // ================= ENCODER =================
    for (int t = 0; t < TT; ++t) {
        const int nxt = cur ^ 1;
        // layer 0
        {
            float ar = 0, az = 0, an = 0;
            const float4* ha = (const float4*)h0m[cur];
            if constexpr (PK) {
                const float4* w0 = (const float4*)(ws + W0T_OFF);
                float4 A0 = w0[0 * HH + j], A1 = w0[1 * HH + j],
                       A2 = w0[2 * HH + j], A3 = w0[3 * HH + j];
                for (int d4 = 0; d4 < HH / 4; d4 += 2) {
                    float4 B0 = w0[((d4 + 1) * 4 + 0) * HH + j];
                    float4 B1 = w0[((d4 + 1) * 4 + 1) * HH + j];
                    float4 B2 = w0[((d4 + 1) * 4 + 2) * HH + j];
                    float4 B3 = w0[((d4 + 1) * 4 + 3) * HH + j];
                    float4 a4 = ha[d4];
                    ar = fmaf(A0.x, a4.x, ar); az = fmaf(A0.y, a4.x, az); an = fmaf(A0.z, a4.x, an);
                    ar = fmaf(A1.x, a4.y, ar); az = fmaf(A1.y, a4.y, az); an = fmaf(A1.z, a4.y, an);
                    ar = fmaf(A2.x, a4.z, ar); az = fmaf(A2.y, a4.z, az); an = fmaf(A2.z, a4.z, an);
                    ar = fmaf(A3.x, a4.w, ar); az = fmaf(A3.y, a4.w, az); an = fmaf(A3.z, a4.w, an);
                    if (d4 + 2 < HH / 4) {
                        A0 = w0[((d4 + 2) * 4 + 0) * HH + j];
                        A1 = w0[((d4 + 2) * 4 + 1) * HH + j];
                        A2 = w0[((d4 + 2) * 4 + 2) * HH + j];
                        A3 = w0[((d4 + 2) * 4 + 3) * HH + j];
                    }
                    float4 b4 = ha[d4 + 1];
                    ar = fmaf(B0.x, b4.x, ar); az = fmaf(B0.y, b4.x, az); an = fmaf(B0.z, b4.x, an);
                    ar = fmaf(B1.x, b4.y, ar); az = fmaf(B1.y, b4.y, az); an = fmaf(B1.z, b4.y, an);
                    ar = fmaf(B2.x, b4.z, ar); az = fmaf(B2.y, b4.z, az); an = fmaf(B2.z, b4.z, an);
                    ar = fmaf(B3.x, b4.w, ar); az = fmaf(B3.y, b4.w, az); an = fmaf(B3.z, b4.w, an);
                }
            } else {
#pragma unroll 4
                for (int d4 = 0; d4 < HH / 4; ++d4) {
                    float4 a = ha[d4];
                    ar = dot4(er[d4], a, ar);
                    az = dot4(ez[d4], a, az);
                    an = dot4(en[d4], a, an);
                }
            }
            float x0 = xl[t][0], x1 = xl[t][1];
            float r = sigf(fmaf(wxr0, x0, fmaf(wxr1, x1, bir)) + ar + bhr);
            float z = sigf(fmaf(wxz0, x0, fmaf(wxz1, x1, biz)) + az + bhz);
            float n = tanhf(fmaf(wxn0, x0, fmaf(wxn1, x1, bin_)) + r * (an + bhn));
            h0m[nxt][j] = (1.0f - z) * n + z * h0m[cur][j];
        }
        __syncthreads();
        // layer 1 (input = new h0)
        {
            float pr, pz, pn, hr, hz, hn;
            if constexpr (PK) {
                gemv6_pk((const float4*)(ws + W1A_OFF), (const float2*)(ws + W1B_OFF),
                         (const float4*)h0m[nxt], (const float4*)h1m[cur], j,
                         pr, pz, pn, hr, hz, hn);
            } else {
                pr = pz = pn = hr = hz = hn = 0;
                const float4* ya = (const float4*)h0m[nxt];
                const float4* ha = (const float4*)h1m[cur];
#pragma unroll 2
                for (int d4 = 0; d4 < HH / 4; ++d4) {
                    float4 a = ya[d4], c = ha[d4];
                    pr = dot4(f1r[d4], a, pr); pz = dot4(f1z[d4], a, pz); pn = dot4(f1n[d4], a, pn);
                    hr = dot4(g1r[d4], c, hr); hz = dot4(g1z[d4], c, hz); hn = dot4(g1n[d4], c, hn);
                }
            }
            float r = sigf(pr + hr + cir);
            float z = sigf(pz + hz + ciz);
            float n = tanhf(pn + cin + r * (hn + chn));
            float hv = (1.0f - z) * n + z * h1m[cur][j];
            h1m[nxt][j] = hv;
            encO[((ll)blk * TT + t) * HH + j] = hv;
        }
        __syncthreads();
        cur ^= 1;
    }

    // ================= DEC-INIT =================
    const float qbj = p.qb[j];
    const float4* qw4 = (const float4*)(p.qW + (ll)j * HH);
    const float4* qt4 = (const float4*)(ws + QTT_OFF);
    {
        const float4* ha = (const float4*)h1m[cur];
        float a0 = 0;
#pragma unroll 4
        for (int d4 = 0; d4 < HH / 4; ++d4) {
            float4 w = PK ? qt4[d4 * HH + j] : qw4[d4];
            a0 = dot4(w, ha[d4], a0);
        }
        qv[j] = a0 + qbj;
    }
    if (tid == 0) tkn = 0;
    __syncthreads();

    // fallback decoder row pointers (DCE'd when PK=1)
    const float4* c0r = (const float4*)(p.dWih0 + (ll)j * 1024 + 512);
    const float4* c0z = (const float4*)(p.dWih0 + (ll)(HH + j) * 1024 + 512);
    const float4* c0n = (const float4*)(p.dWih0 + (ll)(2 * HH + j) * 1024 + 512);
    const float4* u0r = (const float4*)(p.dWhh0 + (ll)j * HH);
    const float4* u0z = (const float4*)(p.dWhh0 + (ll)(HH + j) * HH);
    const float4* u0n = (const float4*)(p.dWhh0 + (ll)(2 * HH + j) * HH);
    const float4* c1r = (const float4*)(p.dWih1 + (ll)j * HH);
    const float4* c1z = (const float4*)(p.dWih1 + (ll)(HH + j) * HH);
    const float4* c1n = (const float4*)(p.dWih1 + (ll)(2 * HH + j) * HH);
    const float4* u1r = (const float4*)(p.dWhh1 + (ll)j * HH);
    const float4* u1z = (const float4*)(p.dWhh1 + (ll)(HH + j) * HH);
    const float4* u1n = (const float4*)(p.dWhh1 + (ll)(2 * HH + j) * HH);
    const float* Trj = Tp + (ll)j * VV;
    const float* Tzj = Tp + (ll)(HH + j) * VV;
    const float* Tnj = Tp + (ll)(2 * HH + j) * VV;
    const float d0r = p.dbih0[j] + p.dbhh0[j];
    const float d0z = p.dbih0[HH + j] + p.dbhh0[HH + j];
    const float d0in = p.dbih0[2 * HH + j];
    const float d0hn = p.dbhh0[2 * HH + j];
    const float d1r = p.dbih1[j] + p.dbhh1[j];
    const float d1z = p.dbih1[HH + j] + p.dbhh1[HH + j];
    const float d1in = p.dbih1[2 * HH + j];
    const float d1hn = p.dbhh1[2 * HH + j];

    // ================= DECODER =================
    for (int s = 0; s < MLEN; ++s) {
        const int nxt = cur ^ 1;
        // scores: pair (t = tid>>1, half = tid&1), shfl-combined
        {
            int t = tid >> 1, h = tid & 1;
            const float4* eRow = (const float4*)(encO + ((ll)blk * TT + t) * HH) + h * 64;
            const float4* q4 = (const float4*)qv + h * 64;
            float a = 0;
#pragma unroll 8
            for (int d4 = 0; d4 < 64; ++d4) a = dot4(q4[d4], eRow[d4], a);
            a += __shfl_down(a, 1);
            if (h == 0) sc[t] = a;
        }
        __syncthreads();
        if (tid < 64) {
            float m = fmaxf(fmaxf(sc[tid], sc[tid + 64]),
                            fmaxf(sc[tid + 128], sc[tid + 192]));
            for (int o = 32; o > 0; o >>= 1) m = fmaxf(m, __shfl_down(m, o));
            if (tid == 0) mred[0] = m;
        }
        __syncthreads();
        if (tid < 256) {
            float e = __expf(sc[tid] - mred[0]);
            sc[tid] = e;
            float ssum = e;
            for (int o = 32; o > 0; o >>= 1) ssum += __shfl_down(ssum, o);
            if ((tid & 63) == 0) mred[1 + (tid >> 6)] = ssum;
        }
        __syncthreads();
        if (tid < 256) {
            float l = mred[1] + mred[2] + mred[3] + mred[4];
            float w = sc[tid] / l;
            sc[tid] = w;
            p.attnO[((ll)blk * MLEN + s) * TT + tid] = w;
        }
        __syncthreads();
        // context
        {
            float c0 = 0;
            const float* e0 = encO + (ll)blk * TT * HH + j;
#pragma unroll 4
            for (int t2 = 0; t2 < TT; ++t2) c0 = fmaf(sc[t2], e0[(ll)t2 * HH], c0);
            cx[j] = c0;
        }
        __syncthreads();
        // G0
        {
            const int tk = tkn;
            float pr, pz, pn, hr, hz, hn;
            if constexpr (PK) {
                gemv6_pk((const float4*)(ws + D0A_OFF), (const float2*)(ws + D0B_OFF),
                         (const float4*)cx, (const float4*)h0m[cur], j,
                         pr, pz, pn, hr, hz, hn);
            } else {
                pr = pz = pn = hr = hz = hn = 0;
                const float4* xa = (const float4*)cx;
                const float4* ha = (const float4*)h0m[cur];
#pragma unroll 2
                for (int d4 = 0; d4 < HH / 4; ++d4) {
                    float4 a = xa[d4], c = ha[d4];
                    pr = dot4(c0r[d4], a, pr); pz = dot4(c0z[d4], a, pz); pn = dot4(c0n[d4], a, pn);
                    hr = dot4(u0r[d4], c, hr); hz = dot4(u0z[d4], c, hz); hn = dot4(u0n[d4], c, hn);
                }
            }
            float r = sigf(Trj[tk] + pr + hr + d0r);
            float z = sigf(Tzj[tk] + pz + hz + d0z);
            float n = tanhf(Tnj[tk] + pn + d0in + r * (hn + d0hn));
            h0m[nxt][j] = (1.0f - z) * n + z * h0m[cur][j];
        }
        __syncthreads();
        // G1
        {
            float pr, pz, pn, hr, hz, hn;
            if constexpr (PK) {
                gemv6_pk((const float4*)(ws + D1A_OFF), (const float2*)(ws + D1B_OFF),
                         (const float4*)h0m[nxt], (const float4*)h1m[cur], j,
                         pr, pz, pn, hr, hz, hn);
            } else {
                pr = pz = pn = hr = hz = hn = 0;
                const float4* ya = (const float4*)h0m[nxt];
                const float4* ha = (const float4*)h1m[cur];
#pragma unroll 2
                for (int d4 = 0; d4 < HH / 4; ++d4) {
                    float4 a = ya[d4], c = ha[d4];
                    pr = dot4(c1r[d4], a, pr); pz = dot4(c1z[d4], a, pz); pn = dot4(c1n[d4], a, pn);
                    hr = dot4(u1r[d4], c, hr); hz = dot4(u1z[d4], c, hz); hn = dot4(u1n[d4], c, hn);
                }
            }
            float r = sigf(pr + hr + d1r);
            float z = sigf(pz + hz + d1z);
            float n = tanhf(pn + d1in + r * (hn + d1hn));
            h1m[nxt][j] = (1.0f - z) * n + z * h1m[cur][j];
        }
        __syncthreads();
        // next-step query
        {
            const float4* ha = (const float4*)h1m[nxt];
            float a0 = 0;
#pragma unroll 4
            for (int d4 = 0; d4 < HH / 4; ++d4) {
                float4 w = PK ? qt4[d4 * HH + j] : qw4[d4];
                a0 = dot4(w, ha[d4], a0);
            }
            qv[j] = a0 + qbj;
        }
        // logits: 16 chunks x 32 v
        {
            int v = tid & 31, ch = tid >> 5;
            const float4* wrow = (const float4*)(p.outW + (ll)v * HH + ch * 32);
            const float4* hrow = (const float4*)(&h1m[nxt][ch * 32]);
            float a = 0;
#pragma unroll
            for (int d4 = 0; d4 < 8; ++d4) a = dot4(wrow[d4], hrow[d4], a);
            red[ch][v] = a;
        }
        __syncthreads();
        if (tid < 32) {
            float a = p.outb[tid];
#pragma unroll
            for (int c = 0; c < 16; ++c) a += red[c][tid];
            lgs[tid] = a;
            p.vecO[((ll)blk * MLEN + s) * VV + tid] = a;
        }
        __syncthreads();
        if (tid == 0) {
            float best = lgs[0];
            int bi = 0;
#pragma unroll
            for (int v = 1; v < VV; ++v) {
                float val = lgs[v];
                if (val > best) { best = val; bi = v; }
            }
            tkn = bi;
        }
        cur ^= 1;
        __syncthreads();
    }

    // ================= final hidden [2][128][512] =================
    p.hidO[(ll)blk * HH + j] = h0m[cur][j];
    p.hidO[(ll)BB * HH + (ll)blk * HH + j] = h1m[cur][j];
}

extern "C" void kernel_launch(void* const* d_in, const int* in_sizes, int n_in,
                              void* d_out, int out_size, void* d_ws, size_t ws_size,
                              hipStream_t stream) {
    (void)in_sizes; (void)n_in; (void)out_size;
    P prm;
    prm.x     = (const float*)d_in[0];
    prm.emb   = (const float*)d_in[1];
    prm.eWih0 = (const float*)d_in[2];
    prm.eWhh0 = (const float*)d_in[3];
    prm.ebih0 = (const float*)d_in[4];
    prm.ebhh0 = (const float*)d_in[5];
    prm.eWih1 = (const float*)d_in[6];
    prm.eWhh1 = (const float*)d_in[7];
    prm.ebih1 = (const float*)d_in[8];
    prm.ebhh1 = (const float*)d_in[9];
    prm.dWih0 = (const float*)d_in[10];
    prm.dWhh0 = (const float*)d_in[11];
    prm.dbih0 = (const float*)d_in[12];
    prm.dbhh0 = (const float*)d_in[13];
    prm.dWih1 = (const float*)d_in[14];
    prm.dWhh1 = (const float*)d_in[15];
    prm.dbih1 = (const float*)d_in[16];
    prm.dbhh1 = (const float*)d_in[17];
    prm.qW    = (const float*)d_in[18];
    prm.qb    = (const float*)d_in[19];
    prm.outW  = (const float*)d_in[20];
    prm.outb  = (const float*)d_in[21];
    prm.ws    = (float*)d_ws;
    prm.vecO  = (float*)d_out;
    prm.hidO  = prm.vecO + (ll)BB * MLEN * VV;
    prm.attnO = prm.hidO + (ll)2 * BB * HH;

    if (ws_size >= (size_t)WS_NEED_BYTES) {
        hipLaunchKernelGGL(kprep, dim3(256), dim3(512), 0, stream, prm);
        hipLaunchKernelGGL(HIP_KERNEL_NAME(kmain<1>), dim3(NBLK), dim3(512), 0, stream, prm);
    } else {
        hipLaunchKernelGGL(HIP_KERNEL_NAME(kmain<0>), dim3(NBLK), dim3(512), 0, stream, prm);
    }
}